// Round 25
// baseline (145.356 us; speedup 1.0000x reference)
//
#include <hip/hip_runtime.h>
#include <hip/hip_fp16.h>

#define IN_C 128
#define NEG 0.2f
#define GAT_EPS 1e-16f
#define NSB_MAX 256        // super-buckets (512 nodes each): supports N <= 131072
#define SB_SHIFT 9         // 512 nodes per super-bucket
#define SB_N 512
#define SRC_MASK 0x1FFFF   // src fits 17 bits (N < 131072)
#define TILE 4096          // edges per partition block
#define CAP_SB 10240       // super-bucket capacity (mean ~8674, sigma ~93 -> 17 sigma)
#define CS_STRIDE 72       // halves; epilogue staging stride (aliases xstage)

typedef _Float16 half8 __attribute__((ext_vector_type(8)));
typedef float f32x4 __attribute__((ext_vector_type(4)));

static __device__ inline unsigned f2h(float f) {
    _Float16 h = (_Float16)f;
    unsigned short u;
    __builtin_memcpy(&u, &h, 2);
    return (unsigned)u;
}

// ---------------- Fused K2: super-bucket partition on blocks [0,egrid) +
// gemm1 (MFMA, async-LDS-staged) on blocks [egrid, egrid+gblks).
// r25: x staged via global_load_lds (8x1KB per wave-tile, fire-and-forget);
// the vmcnt(0) drain at __syncthreads guarantees arrival. Source pre-swizzled
// (p ^ ((p>>9&7)<<4)) so stride-512 ds_reads are bank-minimal, LDS linear.
__global__ __launch_bounds__(256) void k2_kernel(
    const float* __restrict__ x, const float* __restrict__ W1,
    const float* __restrict__ att_s1, const float* __restrict__ att_d1,
    float* __restrict__ hp, __half* __restrict__ a_src1, float* __restrict__ a_dst1,
    const int* __restrict__ ei, int* __restrict__ sbCnt, unsigned* __restrict__ ebuf,
    int E, int Etot, int NSB, int N, int egrid)
{
    __shared__ __align__(16) char smem[49664];   // 16K bfrag + 32K xstage + 0.5K att
    int tid = threadIdx.x;

    if ((int)blockIdx.x < egrid) {
        // ---- partition branch: bin by super-bucket sb = dst >> 9 ----
        int* lcnt  = (int*)smem;            // NSB_MAX
        int* lbase = lcnt + NSB_MAX;        // NSB_MAX
        for (int i = tid; i < NSB; i += 256) lcnt[i] = 0;
        __syncthreads();
        int base = (int)blockIdx.x * TILE;
        for (int k = tid; k < TILE; k += 256) {
            int e = base + k;
            if (e < Etot) {
                int dst = (e < E) ? ei[E + e] : (e - E);   // self-loops appended
                atomicAdd(&lcnt[dst >> SB_SHIFT], 1);
            }
        }
        __syncthreads();
        for (int i = tid; i < NSB; i += 256) {
            int c = lcnt[i];
            lbase[i] = c ? (i * CAP_SB + atomicAdd(&sbCnt[i], c)) : 0;
        }
        __syncthreads();
        for (int i = tid; i < NSB; i += 256) lcnt[i] = 0;   // reuse as rank cursor
        __syncthreads();
        for (int k = tid; k < TILE; k += 256) {
            int e = base + k;
            if (e < Etot) {
                int src, dst;
                if (e < E) { src = ei[e]; dst = ei[E + e]; }
                else       { src = dst = e - E; }
                int b = dst >> SB_SHIFT;
                int r = atomicAdd(&lcnt[b], 1);
                int pos = lbase[b] + r;
                if (pos < (b + 1) * CAP_SB)   // overflow clamp (~17 sigma)
                    ebuf[pos] = ((unsigned)(dst & (SB_N - 1)) << 17) | (unsigned)src;
            }
        }
        return;
    }

    // ---- gemm1 branch: one wave per 16-node tile, async staged ----
    _Float16* bfrag = (_Float16*)smem;                   // 16 KB
    float* attS = (float*)(smem + 16384 + 32768);
    float* attD = attS + 64;
    int lane = tid & 63, wid = tid >> 6;
    char* xstage_w = smem + 16384 + wid * 8192;          // wave-private 8 KB

    int ntiles = (N + 15) >> 4;
    int gb = (int)blockIdx.x - egrid;
    int t0 = (gb << 2) + wid;
    bool havet = (t0 < ntiles);
    int sbase_row = 0;
    if (havet) {
        int n0 = t0 << 4;
        sbase_row = (n0 + 16 <= N) ? n0 : (N - 16);   // clamp (dup-writes identical)
        const char* tb = (const char*)x + (size_t)sbase_row * 512;
        #pragma unroll
        for (int i = 0; i < 8; ++i) {
            int p = i * 1024 + lane * 16;
            int sp = p ^ (((p >> 9) & 7) << 4);       // involutive source swizzle
            __builtin_amdgcn_global_load_lds(
                (const __attribute__((address_space(1))) void*)(tb + sp),
                (__attribute__((address_space(3))) void*)(xstage_w + (i << 10)),
                16, 0, 0);
        }
    }
    if (tid < 64) { attS[tid] = att_s1[tid]; attD[tid] = att_d1[tid]; }
    // B frags: f=(k0*4+nt); lane holds W1[k0*32+(l>>4)*8+j][nt*16+(l&15)]
    for (int idx = tid; idx < 8192; idx += 256) {
        int f = idx >> 9;
        int l = (idx >> 3) & 63;
        int j = idx & 7;
        int k0 = f >> 2, nt = f & 3;
        int row = k0 * 32 + ((l >> 4) << 3) + j;
        int col = (nt << 4) + (l & 15);
        bfrag[idx] = (_Float16)W1[row * 64 + col];
    }
    __syncthreads();   // vmcnt(0)+lgkmcnt(0) drain: xstage AND bfrag both ready

    if (!havet) return;
    int mrow = lane & 15;
    int kgrp = lane >> 4;
    const half8* bf8 = (const half8*)bfrag;
    int swm = (mrow & 7) << 4;
    f32x4 accs[4] = {};
    #pragma unroll
    for (int k0 = 0; k0 < 4; ++k0) {
        int base = mrow * 512 + (kgrp << 5) + (k0 << 7);   // bit4 always 0
        int a1 = base ^ swm;
        float4 xa = *(const float4*)(xstage_w + a1);
        float4 xb = *(const float4*)(xstage_w + (a1 ^ 16));
        half8 a;
        a[0] = (_Float16)xa.x; a[1] = (_Float16)xa.y;
        a[2] = (_Float16)xa.z; a[3] = (_Float16)xa.w;
        a[4] = (_Float16)xb.x; a[5] = (_Float16)xb.y;
        a[6] = (_Float16)xb.z; a[7] = (_Float16)xb.w;
        #pragma unroll
        for (int nt = 0; nt < 4; ++nt)
            accs[nt] = __builtin_amdgcn_mfma_f32_16x16x32_f16(a, bf8[(k0 * 4 + nt) * 64 + lane], accs[nt], 0, 0, 0);
    }
    // epilogue: stage buffer is dead (DS in-order per wave) -> reuse as csw
    _Float16* csw = (_Float16*)xstage_w;
    // C/D layout: col = lane&15 (node), row = (lane>>4)*4+reg [HW-verified]
    #pragma unroll
    for (int r = 0; r < 4; ++r) {
        int row = (kgrp << 2) + r;
        csw[row * CS_STRIDE +  0 + mrow] = (_Float16)accs[0][r];
        csw[row * CS_STRIDE + 16 + mrow] = (_Float16)accs[1][r];
        csw[row * CS_STRIDE + 32 + mrow] = (_Float16)accs[2][r];
        csw[row * CS_STRIDE + 48 + mrow] = (_Float16)accs[3][r];
    }
    asm volatile("s_waitcnt lgkmcnt(0)" ::: "memory");   // wave-wide LDS RAW fence
    // pass A: copy 16 fp16 (32 B) per lane: node = lane>>2, quad = lane&3
    {
        int node = lane >> 2, cq = lane & 3;
        int n = sbase_row + node;
        if (n < N) {
            const int4* src = (const int4*)(csw + node * CS_STRIDE + (cq << 4));
            int4 v0 = src[0];
            int4 v1 = src[1];
            char* dst = (char*)(hp + (size_t)n * 32) + (cq << 5);
            ((int4*)dst)[0] = v0;
            ((int4*)dst)[1] = v1;
        }
    }
    // pass B: a_src/a_dst per (node, head) from fp16 values
    #pragma unroll
    for (int pr = 0; pr < 2; ++pr) {
        int node = (pr << 3) + (lane >> 3), head = lane & 7;
        int n = sbase_row + node;
        if (n < N) {
            const half8* hv = (const half8*)(csw + node * CS_STRIDE + (head << 3));
            half8 v = *hv;
            float s = 0.f, d = 0.f;
            #pragma unroll
            for (int c = 0; c < 8; ++c) {
                float vv = (float)v[c];
                s = fmaf(vv, attS[(head << 3) + c], s);
                d = fmaf(vv, attD[(head << 3) + c], d);
            }
            a_src1[n * 8 + head] = __float2half(s);
            a_dst1[n * 8 + head] = d;
        }
    }
}

// ---------------- super-bucket counting sort (round-24 proven, unchanged)
__global__ __launch_bounds__(512) void sb_sort_kernel(
    const unsigned* __restrict__ ebuf, const int* __restrict__ sbCnt,
    int2* __restrict__ rowse, int* __restrict__ esrc, int N)
{
    __shared__ int lhist[SB_N];
    __shared__ int lstart[SB_N];
    __shared__ int wsums[8];
    int blk = blockIdx.x, t = threadIdx.x;
    int e0 = blk * CAP_SB;
    int cnt = sbCnt[blk]; if (cnt > CAP_SB) cnt = CAP_SB;
    int e1 = e0 + cnt;
    lhist[t] = 0;
    __syncthreads();
    for (int k = e0 + t; k < e1; k += SB_N)
        atomicAdd(&lhist[ebuf[k] >> 17], 1);
    __syncthreads();
    int lane = t & 63, wv = t >> 6;
    int v = lhist[t];
    int s = v;
    for (int off = 1; off < 64; off <<= 1) {
        int u = __shfl_up(s, off);
        if (lane >= off) s += u;
    }
    if (lane == 63) wsums[wv] = s;
    __syncthreads();
    if (t < 64) {
        int ws = (lane < 8) ? wsums[lane] : 0;
        for (int off = 1; off < 8; off <<= 1) {
            int u = __shfl_up(ws, off);
            if (lane >= off) ws += u;
        }
        if (lane < 8) wsums[lane] = ws;
    }
    __syncthreads();
    int woff = (wv > 0) ? wsums[wv - 1] : 0;
    int excl = woff + s - v;
    lstart[t] = excl;
    int n = (blk << SB_SHIFT) + t;
    if (n < N) rowse[n] = make_int2(e0 + excl, e0 + excl + v);
    __syncthreads();
    lhist[t] = 0;
    __syncthreads();
    for (int k = e0 + t; k < e1; k += SB_N) {
        unsigned pk = ebuf[k];
        int d = pk >> 17;
        int r = atomicAdd(&lhist[d], 1);
        esrc[e0 + lstart[d] + r] = (int)(pk & SRC_MASK);
    }
}

// ---------------- Fused agg1 + gemm2 (round-15 proven structure, unchanged)
__global__ __launch_bounds__(256) void agg1g2_kernel(
    const int* __restrict__ esrc, const int2* __restrict__ rowse,
    const float* __restrict__ hp, const __half* __restrict__ a_src1,
    const float* __restrict__ a_dst1, const float* __restrict__ b1,
    const float* __restrict__ W2, const float* __restrict__ att_s2,
    const float* __restrict__ att_d2, __half* __restrict__ h2w,
    float* __restrict__ a_src2, float* __restrict__ a_dst2, int N)
{
    __shared__ _Float16 w2frag[1024];          // 2 KB
    __shared__ _Float16 h2s[4][16][64];        // 8 KB, wave-private sections
    __shared__ float cs[4][16 * 20];           // 5 KB epilogue staging
    int tid = threadIdx.x;
    for (int idx = tid; idx < 1024; idx += 256) {
        int f = idx >> 9, l = (idx >> 3) & 63, j = idx & 7;
        int row = f * 32 + ((l >> 4) << 3) + j;   // same k-map as A-pack
        int col = l & 15;
        w2frag[idx] = (_Float16)W2[row * 16 + col];
    }
    __syncthreads();   // only barrier: w2frag ready

    int lane = tid & 63, wid = tid >> 6;
    int half = lane >> 5, c2 = lane & 31;
    int h = c2 >> 2;                 // fma-role head
    int ch = c2 & 7;                 // compute-role head
    int sbase = half * 32 + h;       // shfl source base
    float2 bb = *(const float2*)(b1 + 2 * c2);
    int mrow = lane & 15, kgrp = lane >> 4;
    const half8* w2bf8 = (const half8*)w2frag;
    float* csw = &cs[wid][0];
    int ech = (lane & 3) << 2;
    float as0 = att_s2[ech], as1 = att_s2[ech + 1], as2 = att_s2[ech + 2], as3 = att_s2[ech + 3];
    float ad0 = att_d2[ech], ad1 = att_d2[ech + 1], ad2 = att_d2[ech + 2], ad3 = att_d2[ech + 3];

    int ngroups = (N + 63) >> 6;
    for (int grp = blockIdx.x; grp < ngroups; grp += gridDim.x) {
        int wbase = (grp << 6) + (wid << 4);
        for (int sub = 0; sub < 8; ++sub) {
            int nloc = (sub << 1) + half;
            int n = wbase + nloc;
            bool act = (n < N);
            int nn = act ? n : 0;
            int2 se = rowse[nn];
            int p = se.x;
            int end = act ? se.y : se.x;
            float ad_f = a_dst1[nn * 8 + h];
            float ad_c = a_dst1[nn * 8 + ch];
            float ax = 0.f, ay = 0.f, wsum = 0.f;
            for (; p + 3 < end; p += 4) {
                int s0 = esrc[p], s1 = esrc[p + 1], s2 = esrc[p + 2], s3 = esrc[p + 3];
                int se_ = (c2 & 16) ? ((c2 & 8) ? s3 : s2) : ((c2 & 8) ? s1 : s0);
                float ac = __half2float(a_src1[se_ * 8 + ch]) + ad_c;
                ac = (ac > 0.f) ? ac : NEG * ac;
                float wl = __expf(ac);
                float w0 = __shfl(wl, sbase);
                float w1 = __shfl(wl, sbase + 8);
                float w2 = __shfl(wl, sbase + 16);
                float w3 = __shfl(wl, sbase + 24);
                __half2 q0 = ((const __half2*)(hp + (size_t)s0 * 32))[c2];
                __half2 q1 = ((const __half2*)(hp + (size_t)s1 * 32))[c2];
                __half2 q2 = ((const __half2*)(hp + (size_t)s2 * 32))[c2];
                __half2 q3 = ((const __half2*)(hp + (size_t)s3 * 32))[c2];
                ax = fmaf(w0, __low2float(q0), ax);  ay = fmaf(w0, __high2float(q0), ay);
                ax = fmaf(w1, __low2float(q1), ax);  ay = fmaf(w1, __high2float(q1), ay);
                ax = fmaf(w2, __low2float(q2), ax);  ay = fmaf(w2, __high2float(q2), ay);
                ax = fmaf(w3, __low2float(q3), ax);  ay = fmaf(w3, __high2float(q3), ay);
                wsum += (w0 + w1) + (w2 + w3);
            }
            for (; p < end; ++p) {
                int s0 = esrc[p];
                float a0 = __half2float(a_src1[s0 * 8 + h]) + ad_f;
                __half2 q0 = ((const __half2*)(hp + (size_t)s0 * 32))[c2];
                a0 = (a0 > 0.f) ? a0 : NEG * a0;
                float w0 = __expf(a0);
                ax = fmaf(w0, __low2float(q0), ax);
                ay = fmaf(w0, __high2float(q0), ay);
                wsum += w0;
            }
            float inv = 1.f / (wsum + GAT_EPS);
            float vx = fmaf(ax, inv, bb.x);
            float vy = fmaf(ay, inv, bb.y);
            vx = (act && vx > 0.f) ? vx : 0.f;
            vy = (act && vy > 0.f) ? vy : 0.f;
            ((__half2*)&h2s[wid][nloc][0])[c2] =
                __halves2half2(__float2half(vx), __float2half(vy));
        }
        // ---- gemm2 phase (wave-private LDS; no cross-wave sync) ----
        asm volatile("s_waitcnt lgkmcnt(0)" ::: "memory");
        f32x4 acc = {0, 0, 0, 0};
        const half8* ar = (const half8*)&h2s[wid][mrow][0];
        acc = __builtin_amdgcn_mfma_f32_16x16x32_f16(ar[kgrp], w2bf8[lane], acc, 0, 0, 0);
        acc = __builtin_amdgcn_mfma_f32_16x16x32_f16(ar[4 + kgrp], w2bf8[64 + lane], acc, 0, 0, 0);
        #pragma unroll
        for (int r = 0; r < 4; ++r)
            csw[((kgrp << 2) + r) * 20 + mrow] = acc[r];
        asm volatile("s_waitcnt lgkmcnt(0)" ::: "memory");
        int node = lane >> 2;
        int n = wbase + node;
        if (n < N) {
            float4 v = *(const float4*)&csw[node * 20 + ech];
            unsigned pk0 = f2h(v.x) | (f2h(v.y) << 16);
            unsigned pk1 = f2h(v.z) | (f2h(v.w) << 16);
            *(int2*)((char*)(h2w + (size_t)n * 16) + (ech << 1)) = make_int2((int)pk0, (int)pk1);
            float s = fmaf(v.x, as0, fmaf(v.y, as1, fmaf(v.z, as2, v.w * as3)));
            float d = fmaf(v.x, ad0, fmaf(v.y, ad1, fmaf(v.z, ad2, v.w * ad3)));
            s += __shfl_xor(s, 1); d += __shfl_xor(d, 1);
            s += __shfl_xor(s, 2); d += __shfl_xor(d, 2);
            if ((lane & 3) == 0) { a_src2[n] = s; a_dst2[n] = d; }
        }
    }
}

// ---------------- Layer 2 aggregation: 8 nodes per wave (8 lanes each), 4-deep.
__global__ __launch_bounds__(256) void agg2_kernel(
    const int* __restrict__ esrc, const int2* __restrict__ rowse,
    const __half* __restrict__ h2w, const float* __restrict__ a_src2,
    const float* __restrict__ a_dst2, const float* __restrict__ b2,
    float* __restrict__ out, int N)
{
    int wslot = (blockIdx.x * 256 + threadIdx.x) >> 6;
    int nw = (gridDim.x * 256) >> 6;
    int lane = threadIdx.x & 63;
    int oct = lane >> 3, c2 = lane & 7;
    for (int base = wslot * 8; base < N; base += nw * 8) {
        int n = base + oct;
        bool act = (n < N);
        int nn = act ? n : 0;
        int2 se = rowse[nn];
        int p = se.x;
        int end = act ? se.y : se.x;
        float ad = a_dst2[nn];
        float ax = 0.f, ay = 0.f, wsum = 0.f;
        for (; p + 3 < end; p += 4) {
            int s0 = esrc[p], s1 = esrc[p + 1], s2 = esrc[p + 2], s3 = esrc[p + 3];
            float a0 = a_src2[s0] + ad;
            float a1 = a_src2[s1] + ad;
            float a2 = a_src2[s2] + ad;
            float a3 = a_src2[s3] + ad;
            __half2 q0 = ((const __half2*)(h2w + (size_t)s0 * 16))[c2];
            __half2 q1 = ((const __half2*)(h2w + (size_t)s1 * 16))[c2];
            __half2 q2 = ((const __half2*)(h2w + (size_t)s2 * 16))[c2];
            __half2 q3 = ((const __half2*)(h2w + (size_t)s3 * 16))[c2];
            a0 = (a0 > 0.f) ? a0 : NEG * a0;
            a1 = (a1 > 0.f) ? a1 : NEG * a1;
            a2 = (a2 > 0.f) ? a2 : NEG * a2;
            a3 = (a3 > 0.f) ? a3 : NEG * a3;
            float w0 = __expf(a0), w1 = __expf(a1), w2 = __expf(a2), w3 = __expf(a3);
            ax = fmaf(w0, __low2float(q0), ax);  ay = fmaf(w0, __high2float(q0), ay);
            ax = fmaf(w1, __low2float(q1), ax);  ay = fmaf(w1, __high2float(q1), ay);
            ax = fmaf(w2, __low2float(q2), ax);  ay = fmaf(w2, __high2float(q2), ay);
            ax = fmaf(w3, __low2float(q3), ax);  ay = fmaf(w3, __high2float(q3), ay);
            wsum += (w0 + w1) + (w2 + w3);
        }
        for (; p < end; ++p) {
            int s0 = esrc[p];
            float a0 = a_src2[s0] + ad;
            __half2 q0 = ((const __half2*)(h2w + (size_t)s0 * 16))[c2];
            a0 = (a0 > 0.f) ? a0 : NEG * a0;
            float w0 = __expf(a0);
            ax = fmaf(w0, __low2float(q0), ax);
            ay = fmaf(w0, __high2float(q0), ay);
            wsum += w0;
        }
        if (act) {
            float inv = 1.f / (wsum + GAT_EPS);
            float2 bb = *(const float2*)(b2 + 2 * c2);
            float2 o;
            o.x = fmaf(ax, inv, bb.x);
            o.y = fmaf(ay, inv, bb.y);
            o.x = o.x > 0.f ? o.x : 0.f;
            o.y = o.y > 0.f ? o.y : 0.f;
            ((float2*)(out + (size_t)n * 16))[c2] = o;
        }
    }
}

extern "C" void kernel_launch(void* const* d_in, const int* in_sizes, int n_in,
                              void* d_out, int out_size, void* d_ws, size_t ws_size,
                              hipStream_t stream)
{
    const float* x      = (const float*)d_in[0];
    const int*   ei     = (const int*)  d_in[1];   // [2,E] int32
    const float* W1     = (const float*)d_in[2];
    const float* att_s1 = (const float*)d_in[3];
    const float* att_d1 = (const float*)d_in[4];
    const float* b1     = (const float*)d_in[5];
    const float* W2     = (const float*)d_in[6];
    const float* att_s2 = (const float*)d_in[7];
    const float* att_d2 = (const float*)d_in[8];
    const float* b2     = (const float*)d_in[9];
    float* out = (float*)d_out;

    int N = in_sizes[0] / IN_C;
    int E = in_sizes[1] / 2;
    int Etot = E + N;
    int NSB = (N + SB_N - 1) >> SB_SHIFT;   // 196 for N=100000 (<= NSB_MAX)

    // workspace: floats, then ints
    float* ws = (float*)d_ws;
    float*  hp      = ws;                               // N*32 (fp16 h, 128 B rows)
    __half* a_src1  = (__half*)(hp + (size_t)N * 32);   // N*8 halves = N*4 floats
    float*  a_dst1  = (float*)a_src1 + (size_t)N * 4;   // N*8
    __half* h2w     = (__half*)(a_dst1 + (size_t)N * 8);// N*16 halves = N*8 floats
    float*  a_src2  = (float*)h2w + (size_t)N * 8;      // N
    float*  a_dst2  = a_src2 + (size_t)N;               // N
    int2* rowse     = (int2*)(a_dst2 + (size_t)N);      // N int2
    int* sbCnt      = (int*)(rowse + N);                // NSB_MAX
    int* esrc       = sbCnt + NSB_MAX;                  // NSB*CAP_SB (strided)
    unsigned* ebuf  = (unsigned*)(esrc + (size_t)NSB * CAP_SB);  // NSB*CAP_SB

    int egrid = (Etot + TILE - 1) / TILE;   // 416 for Etot=1.7M
    int ntiles = (N + 15) >> 4;             // 6250
    int gblks = (ntiles + 3) >> 2;          // 1563 (1 tile per wave, 4 waves/block)

    hipMemsetAsync(sbCnt, 0, NSB_MAX * sizeof(int), stream);
    // K2: partition (blocks [0,egrid)) + gemm1 (blocks [egrid, egrid+gblks))
    k2_kernel<<<egrid + gblks, 256, 0, stream>>>(
        x, W1, att_s1, att_d1, hp, a_src1, a_dst1, ei, sbCnt, ebuf,
        E, Etot, NSB, N, egrid);
    sb_sort_kernel<<<NSB, 512, 0, stream>>>(ebuf, sbCnt, rowse, esrc, N);

    // fused agg1 + gemm2
    {
        int ngroups = (N + 63) >> 6;   // 1563
        agg1g2_kernel<<<ngroups, 256, 0, stream>>>(
            esrc, rowse, hp, a_src1, a_dst1, b1,
            W2, att_s2, att_d2, h2w, a_src2, a_dst2, N);
    }
    agg2_kernel<<<1024, 256, 0, stream>>>(esrc, rowse, h2w, a_src2, a_dst2, b2, out, N);
}

// Round 26
// 141.402 us; speedup vs baseline: 1.0280x; 1.0280x over previous
//
#include <hip/hip_runtime.h>
#include <hip/hip_fp16.h>

#define IN_C 128
#define NEG 0.2f
#define GAT_EPS 1e-16f
#define NSB_MAX 256        // super-buckets (512 nodes each): supports N <= 131072
#define SB_SHIFT 9         // 512 nodes per super-bucket
#define SB_N 512
#define SRC_MASK 0x1FFFF   // src fits 17 bits (N < 131072)
#define TILE 4096          // edges per partition block (runs ~21 edges = 84 B > line)
#define GEMM_BLKS 782      // gemm1 blocks inside fused K2 (1 tile-pair per wave)
#define CAP_SB 10240       // super-bucket capacity (mean ~8674, sigma ~93 -> 17 sigma)
#define CS_STRIDE 72       // halves; 144 B rows keep 16 B alignment for pass-A reads

typedef _Float16 half8 __attribute__((ext_vector_type(8)));
typedef float f32x4 __attribute__((ext_vector_type(4)));

static __device__ inline unsigned f2h(float f) {
    _Float16 h = (_Float16)f;
    unsigned short u;
    __builtin_memcpy(&u, &h, 2);
    return (unsigned)u;
}

// ---------------- Fused K2: super-bucket partition on blocks [0,egrid) +
// gemm1 (MFMA, 2-tile) on blocks [egrid, egrid+GEMM_BLKS).
__global__ __launch_bounds__(256) void k2_kernel(
    const float* __restrict__ x, const float* __restrict__ W1,
    const float* __restrict__ att_s1, const float* __restrict__ att_d1,
    float* __restrict__ hp, __half* __restrict__ a_src1, float* __restrict__ a_dst1,
    const int* __restrict__ ei, int* __restrict__ sbCnt, unsigned* __restrict__ ebuf,
    int E, int Etot, int NSB, int N, int egrid)
{
    __shared__ __align__(16) char smem[26112];
    int tid = threadIdx.x;

    if ((int)blockIdx.x < egrid) {
        // ---- partition branch: bin by super-bucket sb = dst >> 9 ----
        int* lcnt  = (int*)smem;            // NSB_MAX
        int* lbase = lcnt + NSB_MAX;        // NSB_MAX
        for (int i = tid; i < NSB; i += 256) lcnt[i] = 0;
        __syncthreads();
        int base = (int)blockIdx.x * TILE;
        for (int k = tid; k < TILE; k += 256) {
            int e = base + k;
            if (e < Etot) {
                int dst = (e < E) ? ei[E + e] : (e - E);   // self-loops appended
                atomicAdd(&lcnt[dst >> SB_SHIFT], 1);
            }
        }
        __syncthreads();
        for (int i = tid; i < NSB; i += 256) {
            int c = lcnt[i];
            lbase[i] = c ? (i * CAP_SB + atomicAdd(&sbCnt[i], c)) : 0;
        }
        __syncthreads();
        for (int i = tid; i < NSB; i += 256) lcnt[i] = 0;   // reuse as rank cursor
        __syncthreads();
        for (int k = tid; k < TILE; k += 256) {
            int e = base + k;
            if (e < Etot) {
                int src, dst;
                if (e < E) { src = ei[e]; dst = ei[E + e]; }
                else       { src = dst = e - E; }
                int b = dst >> SB_SHIFT;
                int r = atomicAdd(&lcnt[b], 1);
                int pos = lbase[b] + r;
                if (pos < (b + 1) * CAP_SB)   // overflow clamp (~17 sigma)
                    ebuf[pos] = ((unsigned)(dst & (SB_N - 1)) << 17) | (unsigned)src;
            }
        }
        return;
    }

    // ---- gemm1 branch: one wave per PAIR of 16-node tiles ----
    _Float16* bfrag = (_Float16*)smem;                    // 16 KB
    _Float16* csbase = (_Float16*)(smem + 16384);         // 4 waves x 16 x CS_STRIDE fp16
    float* attS = (float*)(smem + 16384 + 9216);
    float* attD = attS + 64;
    if (tid < 64) { attS[tid] = att_s1[tid]; attD[tid] = att_d1[tid]; }
    // B frags: f=(k0*4+nt); lane holds W1[k0*32+(l>>4)*8+j][nt*16+(l&15)]
    for (int idx = tid; idx < 8192; idx += 256) {
        int f = idx >> 9;
        int l = (idx >> 3) & 63;
        int j = idx & 7;
        int k0 = f >> 2, nt = f & 3;
        int row = k0 * 32 + ((l >> 4) << 3) + j;
        int col = (nt << 4) + (l & 15);
        bfrag[idx] = (_Float16)W1[row * 64 + col];
    }
    __syncthreads();

    int lane = tid & 63, wid = tid >> 6;
    _Float16* csw = csbase + wid * (16 * CS_STRIDE);
    int mrow = lane & 15;
    int kgrp = lane >> 4;
    const half8* bf8 = (const half8*)bfrag;
    int ntiles = (N + 15) >> 4;
    int gb = (int)blockIdx.x - egrid;
    for (int t0 = (gb << 3) + (wid << 1); t0 < ntiles; t0 += (GEMM_BLKS << 3)) {
        bool has1 = (t0 + 1) < ntiles;
        int n0 = t0 << 4;
        int arow0 = n0 + mrow;        if (arow0 >= N) arow0 = N - 1;
        int arow1 = n0 + 16 + mrow;   if (arow1 >= N) arow1 = N - 1;
        const float* xr0 = x + (size_t)arow0 * IN_C + (kgrp << 3);
        const float* xr1 = x + (size_t)arow1 * IN_C + (kgrp << 3);
        f32x4 accs[2][4] = {};
        #pragma unroll
        for (int k0 = 0; k0 < 4; ++k0) {
            float4 xa0 = *(const float4*)(xr0 + k0 * 32);
            float4 xb0 = *(const float4*)(xr0 + k0 * 32 + 4);
            float4 xa1 = *(const float4*)(xr1 + k0 * 32);
            float4 xb1 = *(const float4*)(xr1 + k0 * 32 + 4);
            half8 a0, a1;
            a0[0] = (_Float16)xa0.x; a0[1] = (_Float16)xa0.y;
            a0[2] = (_Float16)xa0.z; a0[3] = (_Float16)xa0.w;
            a0[4] = (_Float16)xb0.x; a0[5] = (_Float16)xb0.y;
            a0[6] = (_Float16)xb0.z; a0[7] = (_Float16)xb0.w;
            a1[0] = (_Float16)xa1.x; a1[1] = (_Float16)xa1.y;
            a1[2] = (_Float16)xa1.z; a1[3] = (_Float16)xa1.w;
            a1[4] = (_Float16)xb1.x; a1[5] = (_Float16)xb1.y;
            a1[6] = (_Float16)xb1.z; a1[7] = (_Float16)xb1.w;
            #pragma unroll
            for (int nt = 0; nt < 4; ++nt) {
                accs[0][nt] = __builtin_amdgcn_mfma_f32_16x16x32_f16(a0, bf8[(k0 * 4 + nt) * 64 + lane], accs[0][nt], 0, 0, 0);
                accs[1][nt] = __builtin_amdgcn_mfma_f32_16x16x32_f16(a1, bf8[(k0 * 4 + nt) * 64 + lane], accs[1][nt], 0, 0, 0);
            }
        }
        // epilogues (wave-private LDS, DS in-order per wave -> no barrier)
        #pragma unroll
        for (int tt = 0; tt < 2; ++tt) {
            if (tt == 1 && !has1) break;
            int nb0 = n0 + (tt << 4);
            // C/D layout: col = lane&15 (node), row = (lane>>4)*4+reg [HW-verified].
            #pragma unroll
            for (int r = 0; r < 4; ++r) {
                int row = (kgrp << 2) + r;
                csw[row * CS_STRIDE +  0 + mrow] = (_Float16)accs[tt][0][r];
                csw[row * CS_STRIDE + 16 + mrow] = (_Float16)accs[tt][1][r];
                csw[row * CS_STRIDE + 32 + mrow] = (_Float16)accs[tt][2][r];
                csw[row * CS_STRIDE + 48 + mrow] = (_Float16)accs[tt][3][r];
            }
            asm volatile("s_waitcnt lgkmcnt(0)" ::: "memory");   // wave-wide LDS RAW fence
            // pass A: copy 16 fp16 (32 B) per lane: node = lane>>2, quad = lane&3
            {
                int node = lane >> 2, cq = lane & 3;
                int n = nb0 + node;
                if (n < N) {
                    const int4* src = (const int4*)(csw + node * CS_STRIDE + (cq << 4));
                    int4 v0 = src[0];
                    int4 v1 = src[1];
                    char* dst = (char*)(hp + (size_t)n * 32) + (cq << 5);
                    ((int4*)dst)[0] = v0;
                    ((int4*)dst)[1] = v1;
                }
            }
            // pass B: a_src/a_dst per (node, head) from fp16 values
            #pragma unroll
            for (int pr = 0; pr < 2; ++pr) {
                int node = (pr << 3) + (lane >> 3), head = lane & 7;
                int n = nb0 + node;
                if (n < N) {
                    const half8* hv = (const half8*)(csw + node * CS_STRIDE + (head << 3));
                    half8 v = *hv;
                    float s = 0.f, d = 0.f;
                    #pragma unroll
                    for (int c = 0; c < 8; ++c) {
                        float vv = (float)v[c];
                        s = fmaf(vv, attS[(head << 3) + c], s);
                        d = fmaf(vv, attD[(head << 3) + c], d);
                    }
                    a_src1[n * 8 + head] = __float2half(s);
                    a_dst1[n * 8 + head] = d;
                }
            }
        }
    }
}

// ---------------- super-bucket counting sort: 1 block (512 thr) per super-bucket
// -> esrc (contiguous per SB) + rowse int2[N]. 196 blocks.
__global__ __launch_bounds__(512) void sb_sort_kernel(
    const unsigned* __restrict__ ebuf, const int* __restrict__ sbCnt,
    int2* __restrict__ rowse, int* __restrict__ esrc, int N)
{
    __shared__ int lhist[SB_N];
    __shared__ int lstart[SB_N];
    __shared__ int wsums[8];
    int blk = blockIdx.x, t = threadIdx.x;
    int e0 = blk * CAP_SB;
    int cnt = sbCnt[blk]; if (cnt > CAP_SB) cnt = CAP_SB;
    int e1 = e0 + cnt;
    lhist[t] = 0;
    __syncthreads();
    for (int k = e0 + t; k < e1; k += SB_N)
        atomicAdd(&lhist[ebuf[k] >> 17], 1);
    __syncthreads();
    int lane = t & 63, wv = t >> 6;
    int v = lhist[t];
    int s = v;
    for (int off = 1; off < 64; off <<= 1) {
        int u = __shfl_up(s, off);
        if (lane >= off) s += u;
    }
    if (lane == 63) wsums[wv] = s;
    __syncthreads();
    if (t < 64) {                        // wave 0 scans the 8 wave sums (inclusive)
        int ws = (lane < 8) ? wsums[lane] : 0;
        for (int off = 1; off < 8; off <<= 1) {
            int u = __shfl_up(ws, off);
            if (lane >= off) ws += u;
        }
        if (lane < 8) wsums[lane] = ws;
    }
    __syncthreads();
    int woff = (wv > 0) ? wsums[wv - 1] : 0;
    int excl = woff + s - v;
    lstart[t] = excl;
    int n = (blk << SB_SHIFT) + t;
    if (n < N) rowse[n] = make_int2(e0 + excl, e0 + excl + v);
    __syncthreads();
    lhist[t] = 0;                        // reuse as rank cursor
    __syncthreads();
    for (int k = e0 + t; k < e1; k += SB_N) {
        unsigned pk = ebuf[k];
        int d = pk >> 17;
        int r = atomicAdd(&lhist[d], 1);
        esrc[e0 + lstart[d] + r] = (int)(pk & SRC_MASK);
    }
}

// ---------------- Fused agg1 + gemm2 (round-15 proven structure, unchanged)
__global__ __launch_bounds__(256) void agg1g2_kernel(
    const int* __restrict__ esrc, const int2* __restrict__ rowse,
    const float* __restrict__ hp, const __half* __restrict__ a_src1,
    const float* __restrict__ a_dst1, const float* __restrict__ b1,
    const float* __restrict__ W2, const float* __restrict__ att_s2,
    const float* __restrict__ att_d2, __half* __restrict__ h2w,
    float* __restrict__ a_src2, float* __restrict__ a_dst2, int N)
{
    __shared__ _Float16 w2frag[1024];          // 2 KB
    __shared__ _Float16 h2s[4][16][64];        // 8 KB, wave-private sections
    __shared__ float cs[4][16 * 20];           // 5 KB epilogue staging
    int tid = threadIdx.x;
    for (int idx = tid; idx < 1024; idx += 256) {
        int f = idx >> 9, l = (idx >> 3) & 63, j = idx & 7;
        int row = f * 32 + ((l >> 4) << 3) + j;   // same k-map as A-pack
        int col = l & 15;
        w2frag[idx] = (_Float16)W2[row * 16 + col];
    }
    __syncthreads();   // only barrier: w2frag ready

    int lane = tid & 63, wid = tid >> 6;
    int half = lane >> 5, c2 = lane & 31;
    int h = c2 >> 2;                 // fma-role head
    int ch = c2 & 7;                 // compute-role head
    int sbase = half * 32 + h;       // shfl source base
    float2 bb = *(const float2*)(b1 + 2 * c2);
    int mrow = lane & 15, kgrp = lane >> 4;
    const half8* w2bf8 = (const half8*)w2frag;
    float* csw = &cs[wid][0];
    int ech = (lane & 3) << 2;
    float as0 = att_s2[ech], as1 = att_s2[ech + 1], as2 = att_s2[ech + 2], as3 = att_s2[ech + 3];
    float ad0 = att_d2[ech], ad1 = att_d2[ech + 1], ad2 = att_d2[ech + 2], ad3 = att_d2[ech + 3];

    int ngroups = (N + 63) >> 6;
    for (int grp = blockIdx.x; grp < ngroups; grp += gridDim.x) {
        int wbase = (grp << 6) + (wid << 4);
        for (int sub = 0; sub < 8; ++sub) {
            int nloc = (sub << 1) + half;
            int n = wbase + nloc;
            bool act = (n < N);
            int nn = act ? n : 0;
            int2 se = rowse[nn];
            int p = se.x;
            int end = act ? se.y : se.x;
            float ad_f = a_dst1[nn * 8 + h];
            float ad_c = a_dst1[nn * 8 + ch];
            float ax = 0.f, ay = 0.f, wsum = 0.f;
            for (; p + 3 < end; p += 4) {
                int s0 = esrc[p], s1 = esrc[p + 1], s2 = esrc[p + 2], s3 = esrc[p + 3];
                int se_ = (c2 & 16) ? ((c2 & 8) ? s3 : s2) : ((c2 & 8) ? s1 : s0);
                float ac = __half2float(a_src1[se_ * 8 + ch]) + ad_c;
                ac = (ac > 0.f) ? ac : NEG * ac;
                float wl = __expf(ac);
                float w0 = __shfl(wl, sbase);
                float w1 = __shfl(wl, sbase + 8);
                float w2 = __shfl(wl, sbase + 16);
                float w3 = __shfl(wl, sbase + 24);
                __half2 q0 = ((const __half2*)(hp + (size_t)s0 * 32))[c2];
                __half2 q1 = ((const __half2*)(hp + (size_t)s1 * 32))[c2];
                __half2 q2 = ((const __half2*)(hp + (size_t)s2 * 32))[c2];
                __half2 q3 = ((const __half2*)(hp + (size_t)s3 * 32))[c2];
                ax = fmaf(w0, __low2float(q0), ax);  ay = fmaf(w0, __high2float(q0), ay);
                ax = fmaf(w1, __low2float(q1), ax);  ay = fmaf(w1, __high2float(q1), ay);
                ax = fmaf(w2, __low2float(q2), ax);  ay = fmaf(w2, __high2float(q2), ay);
                ax = fmaf(w3, __low2float(q3), ax);  ay = fmaf(w3, __high2float(q3), ay);
                wsum += (w0 + w1) + (w2 + w3);
            }
            for (; p < end; ++p) {
                int s0 = esrc[p];
                float a0 = __half2float(a_src1[s0 * 8 + h]) + ad_f;
                __half2 q0 = ((const __half2*)(hp + (size_t)s0 * 32))[c2];
                a0 = (a0 > 0.f) ? a0 : NEG * a0;
                float w0 = __expf(a0);
                ax = fmaf(w0, __low2float(q0), ax);
                ay = fmaf(w0, __high2float(q0), ay);
                wsum += w0;
            }
            float inv = 1.f / (wsum + GAT_EPS);
            float vx = fmaf(ax, inv, bb.x);
            float vy = fmaf(ay, inv, bb.y);
            vx = (act && vx > 0.f) ? vx : 0.f;
            vy = (act && vy > 0.f) ? vy : 0.f;
            ((__half2*)&h2s[wid][nloc][0])[c2] =
                __halves2half2(__float2half(vx), __float2half(vy));
        }
        // ---- gemm2 phase (wave-private LDS; no cross-wave sync) ----
        asm volatile("s_waitcnt lgkmcnt(0)" ::: "memory");
        f32x4 acc = {0, 0, 0, 0};
        const half8* ar = (const half8*)&h2s[wid][mrow][0];
        acc = __builtin_amdgcn_mfma_f32_16x16x32_f16(ar[kgrp], w2bf8[lane], acc, 0, 0, 0);
        acc = __builtin_amdgcn_mfma_f32_16x16x32_f16(ar[4 + kgrp], w2bf8[64 + lane], acc, 0, 0, 0);
        #pragma unroll
        for (int r = 0; r < 4; ++r)
            csw[((kgrp << 2) + r) * 20 + mrow] = acc[r];
        asm volatile("s_waitcnt lgkmcnt(0)" ::: "memory");
        int node = lane >> 2;
        int n = wbase + node;
        if (n < N) {
            float4 v = *(const float4*)&csw[node * 20 + ech];
            unsigned pk0 = f2h(v.x) | (f2h(v.y) << 16);
            unsigned pk1 = f2h(v.z) | (f2h(v.w) << 16);
            *(int2*)((char*)(h2w + (size_t)n * 16) + (ech << 1)) = make_int2((int)pk0, (int)pk1);
            float s = fmaf(v.x, as0, fmaf(v.y, as1, fmaf(v.z, as2, v.w * as3)));
            float d = fmaf(v.x, ad0, fmaf(v.y, ad1, fmaf(v.z, ad2, v.w * ad3)));
            s += __shfl_xor(s, 1); d += __shfl_xor(d, 1);
            s += __shfl_xor(s, 2); d += __shfl_xor(d, 2);
            if ((lane & 3) == 0) { a_src2[n] = s; a_dst2[n] = d; }
        }
    }
}

// ---------------- Layer 2 aggregation: 8 nodes per wave (8 lanes each), 4-deep.
__global__ __launch_bounds__(256) void agg2_kernel(
    const int* __restrict__ esrc, const int2* __restrict__ rowse,
    const __half* __restrict__ h2w, const float* __restrict__ a_src2,
    const float* __restrict__ a_dst2, const float* __restrict__ b2,
    float* __restrict__ out, int N)
{
    int wslot = (blockIdx.x * 256 + threadIdx.x) >> 6;
    int nw = (gridDim.x * 256) >> 6;
    int lane = threadIdx.x & 63;
    int oct = lane >> 3, c2 = lane & 7;
    for (int base = wslot * 8; base < N; base += nw * 8) {
        int n = base + oct;
        bool act = (n < N);
        int nn = act ? n : 0;
        int2 se = rowse[nn];
        int p = se.x;
        int end = act ? se.y : se.x;
        float ad = a_dst2[nn];
        float ax = 0.f, ay = 0.f, wsum = 0.f;
        for (; p + 3 < end; p += 4) {
            int s0 = esrc[p], s1 = esrc[p + 1], s2 = esrc[p + 2], s3 = esrc[p + 3];
            float a0 = a_src2[s0] + ad;
            float a1 = a_src2[s1] + ad;
            float a2 = a_src2[s2] + ad;
            float a3 = a_src2[s3] + ad;
            __half2 q0 = ((const __half2*)(h2w + (size_t)s0 * 16))[c2];
            __half2 q1 = ((const __half2*)(h2w + (size_t)s1 * 16))[c2];
            __half2 q2 = ((const __half2*)(h2w + (size_t)s2 * 16))[c2];
            __half2 q3 = ((const __half2*)(h2w + (size_t)s3 * 16))[c2];
            a0 = (a0 > 0.f) ? a0 : NEG * a0;
            a1 = (a1 > 0.f) ? a1 : NEG * a1;
            a2 = (a2 > 0.f) ? a2 : NEG * a2;
            a3 = (a3 > 0.f) ? a3 : NEG * a3;
            float w0 = __expf(a0), w1 = __expf(a1), w2 = __expf(a2), w3 = __expf(a3);
            ax = fmaf(w0, __low2float(q0), ax);  ay = fmaf(w0, __high2float(q0), ay);
            ax = fmaf(w1, __low2float(q1), ax);  ay = fmaf(w1, __high2float(q1), ay);
            ax = fmaf(w2, __low2float(q2), ax);  ay = fmaf(w2, __high2float(q2), ay);
            ax = fmaf(w3, __low2float(q3), ax);  ay = fmaf(w3, __high2float(q3), ay);
            wsum += (w0 + w1) + (w2 + w3);
        }
        for (; p < end; ++p) {
            int s0 = esrc[p];
            float a0 = a_src2[s0] + ad;
            __half2 q0 = ((const __half2*)(h2w + (size_t)s0 * 16))[c2];
            a0 = (a0 > 0.f) ? a0 : NEG * a0;
            float w0 = __expf(a0);
            ax = fmaf(w0, __low2float(q0), ax);
            ay = fmaf(w0, __high2float(q0), ay);
            wsum += w0;
        }
        if (act) {
            float inv = 1.f / (wsum + GAT_EPS);
            float2 bb = *(const float2*)(b2 + 2 * c2);
            float2 o;
            o.x = fmaf(ax, inv, bb.x);
            o.y = fmaf(ay, inv, bb.y);
            o.x = o.x > 0.f ? o.x : 0.f;
            o.y = o.y > 0.f ? o.y : 0.f;
            ((float2*)(out + (size_t)n * 16))[c2] = o;
        }
    }
}

extern "C" void kernel_launch(void* const* d_in, const int* in_sizes, int n_in,
                              void* d_out, int out_size, void* d_ws, size_t ws_size,
                              hipStream_t stream)
{
    const float* x      = (const float*)d_in[0];
    const int*   ei     = (const int*)  d_in[1];   // [2,E] int32
    const float* W1     = (const float*)d_in[2];
    const float* att_s1 = (const float*)d_in[3];
    const float* att_d1 = (const float*)d_in[4];
    const float* b1     = (const float*)d_in[5];
    const float* W2     = (const float*)d_in[6];
    const float* att_s2 = (const float*)d_in[7];
    const float* att_d2 = (const float*)d_in[8];
    const float* b2     = (const float*)d_in[9];
    float* out = (float*)d_out;

    int N = in_sizes[0] / IN_C;
    int E = in_sizes[1] / 2;
    int Etot = E + N;
    int NSB = (N + SB_N - 1) >> SB_SHIFT;   // 196 for N=100000 (<= NSB_MAX)

    // workspace: floats, then ints
    float* ws = (float*)d_ws;
    float*  hp      = ws;                               // N*32 (fp16 h, 128 B rows)
    __half* a_src1  = (__half*)(hp + (size_t)N * 32);   // N*8 halves = N*4 floats
    float*  a_dst1  = (float*)a_src1 + (size_t)N * 4;   // N*8
    __half* h2w     = (__half*)(a_dst1 + (size_t)N * 8);// N*16 halves = N*8 floats
    float*  a_src2  = (float*)h2w + (size_t)N * 8;      // N
    float*  a_dst2  = a_src2 + (size_t)N;               // N
    int2* rowse     = (int2*)(a_dst2 + (size_t)N);      // N int2
    int* sbCnt      = (int*)(rowse + N);                // NSB_MAX
    int* esrc       = sbCnt + NSB_MAX;                  // NSB*CAP_SB (strided)
    unsigned* ebuf  = (unsigned*)(esrc + (size_t)NSB * CAP_SB);  // NSB*CAP_SB

    int egrid = (Etot + TILE - 1) / TILE;   // 416 for Etot=1.7M

    hipMemsetAsync(sbCnt, 0, NSB_MAX * sizeof(int), stream);
    // K2: partition (blocks [0,egrid)) + gemm1 (blocks [egrid, egrid+GEMM_BLKS))
    k2_kernel<<<egrid + GEMM_BLKS, 256, 0, stream>>>(
        x, W1, att_s1, att_d1, hp, a_src1, a_dst1, ei, sbCnt, ebuf,
        E, Etot, NSB, N, egrid);
    sb_sort_kernel<<<NSB, 512, 0, stream>>>(ebuf, sbCnt, rowse, esrc, N);

    // fused agg1 + gemm2
    {
        int ngroups = (N + 63) >> 6;   // 1563
        agg1g2_kernel<<<ngroups, 256, 0, stream>>>(
            esrc, rowse, hp, a_src1, a_dst1, b1,
            W2, att_s2, att_d2, h2w, a_src2, a_dst2, N);
    }
    agg2_kernel<<<1024, 256, 0, stream>>>(esrc, rowse, h2w, a_src2, a_dst2, b2, out, N);
}